// Round 6
// baseline (432.907 us; speedup 1.0000x reference)
//
#include <hip/hip_runtime.h>

#define E_EDGES   1000000
#define NNODES    2048
#define NROWS     65536          // B*N distinct node rows
#define HCH       128
#define KP        136            // w1t row stride in bf16 (cols 0..131 valid)
#define ZVEC      (32 * 2048 * 64 / 4)   // 1048576 float4s of z
#define ZBLK      2048
#define WBLK      66             // 66*256 = 132*128 w1t transpose elements
#define SGRID     2048           // stats/out grid
#define NIT       62500          // 1e6 edges / 16 per block-iter (exact)
#define NSPREAD   8

typedef short  shortx8 __attribute__((ext_vector_type(8)));
typedef float  floatx4 __attribute__((ext_vector_type(4)));

__device__ __forceinline__ unsigned short f2bf(float f) {
  union { float f; unsigned int u; } v; v.f = f;
  unsigned int r = (v.u + 0x7fffu + ((v.u >> 16) & 1u)) >> 16;
  return (unsigned short)r;
}
__device__ __forceinline__ float bf2f(unsigned short u) {
  union { unsigned int i; float f; } v; v.i = ((unsigned int)u) << 16; return v.f;
}
__device__ __forceinline__ void SB() { __builtin_amdgcn_sched_barrier(0); }

// ---------------------------------------------------------------- prep ----
// zb = bf16(z); w1t[n][k] = bf16(W1[k][n]) for k<132; gstats zeroed.
__global__ void k_prep(const float* __restrict__ z, const float* __restrict__ W1,
                       unsigned short* __restrict__ zb, unsigned short* __restrict__ w1t,
                       float* __restrict__ gstats) {
  int bid = blockIdx.x;
  if (bid < ZBLK) {
    const float4* z4 = (const float4*)z;
    ushort4* zb4 = (ushort4*)zb;
    for (int i = bid * 256 + threadIdx.x; i < ZVEC; i += ZBLK * 256) {
      float4 v = z4[i];
      ushort4 o;
      o.x = f2bf(v.x); o.y = f2bf(v.y); o.z = f2bf(v.z); o.w = f2bf(v.w);
      zb4[i] = o;
    }
  } else if (bid < ZBLK + WBLK) {
    int idx = (bid - ZBLK) * 256 + threadIdx.x;   // 0..16895 = 132*128
    int k = idx >> 7, n = idx & 127;              // coalesced read of W1
    w1t[n * KP + k] = f2bf(W1[idx]);
  } else {
    for (int i = threadIdx.x; i < NSPREAD * 2 * HCH; i += 256) gstats[i] = 0.f;
  }
}

// --------------------------------------------------------------- ygemm ----
// Ys[n][c] = (z[n] @ W1[0:64]) + b1[c];  Yd[n][c] = z[n] @ W1[64:128].
// Direct-B MFMA (no LDS): A = w1t fragments (static), B = node-row chunks.
// Wave: 16 nodes x 64 ch x {Ys,Yd}. Block = 32 nodes. 2048 blocks.
__global__ __launch_bounds__(256, 2)
void k_ygemm(const unsigned short* __restrict__ zb,
             const unsigned short* __restrict__ w1t,
             const float* __restrict__ b1,
             unsigned short* __restrict__ Ys, unsigned short* __restrict__ Yd) {
  const int tid  = threadIdx.x;
  const int lane = tid & 63;
  const int wave = tid >> 6;
  const int l15  = lane & 15;
  const int quad = lane >> 4;
  const int chh  = wave & 1;        // channel half (0..63 / 64..127)
  const int ndh  = wave >> 1;       // node half within block
  const int nb   = blockIdx.x * 32 + ndh * 16;

  // A fragments: A[row=ch][k]; o=0 -> W1 rows 0..63 (src), o=1 -> 64..127 (dst)
  shortx8 af[2][4][2];
#pragma unroll
  for (int o = 0; o < 2; ++o)
#pragma unroll
    for (int nt = 0; nt < 4; ++nt)
#pragma unroll
      for (int kk = 0; kk < 2; ++kk)
        af[o][nt][kk] = *(const shortx8*)(
            w1t + (chh * 64 + nt * 16 + l15) * KP + o * 64 + kk * 32 + quad * 8);

  float b1v[4][4];
#pragma unroll
  for (int nt = 0; nt < 4; ++nt)
#pragma unroll
    for (int r = 0; r < 4; ++r)
      b1v[nt][r] = b1[chh * 64 + nt * 16 + quad * 4 + r];

  // B fragments: B[k][col=node]: lane holds zb[node=l15-row][k-chunk]
  shortx8 bfv[2];
#pragma unroll
  for (int kk = 0; kk < 2; ++kk)
    bfv[kk] = *(const shortx8*)(zb + (nb + l15) * 64 + kk * 32 + quad * 8);

  floatx4 acc[2][4];
#pragma unroll
  for (int o = 0; o < 2; ++o)
#pragma unroll
    for (int nt = 0; nt < 4; ++nt)
      acc[o][nt] = (floatx4){0.f, 0.f, 0.f, 0.f};

#pragma unroll
  for (int kk = 0; kk < 2; ++kk)
#pragma unroll
    for (int o = 0; o < 2; ++o)
#pragma unroll
      for (int nt = 0; nt < 4; ++nt)
        acc[o][nt] = __builtin_amdgcn_mfma_f32_16x16x32_bf16(
            af[o][nt][kk], bfv[kk], acc[o][nt], 0, 0, 0);

#pragma unroll
  for (int nt = 0; nt < 4; ++nt)
#pragma unroll
    for (int r = 0; r < 4; ++r)
      acc[0][nt][r] += b1v[nt][r];          // bias folded into Ys

  // D layout: col=l15=node, row=quad*4+r = ch offset in 16-group
#pragma unroll
  for (int o = 0; o < 2; ++o) {
    unsigned short* Y = o ? Yd : Ys;
#pragma unroll
    for (int nt = 0; nt < 4; ++nt) {
      ushort4 ov;
      ov.x = f2bf(acc[o][nt][0]); ov.y = f2bf(acc[o][nt][1]);
      ov.z = f2bf(acc[o][nt][2]); ov.w = f2bf(acc[o][nt][3]);
      *(ushort4*)(Y + (nb + l15) * HCH + chh * 64 + nt * 16 + quad * 4) = ov;
    }
  }
}

// --------------------------------------------------------------- stats ----
// Lane (e2 = lane>>4, c16 = lane&15): edge e2 of the wave's 4, channel slice
// c16*8..+8. Per iter: gather Ys[src] / Yd[dst] 16B chunks (fully coalesced:
// 16 lanes = one 256B row), h = Ys+Yd+attr@W1a, accumulate sum/sq.
// 2-deep prefetch; no LDS, no barriers; occupancy 4 blocks/CU.
__global__ __launch_bounds__(256, 4)
void k_stats(const unsigned short* __restrict__ Ys, const unsigned short* __restrict__ Yd,
             const unsigned short* __restrict__ w1t,
             const int* __restrict__ ei, const float* __restrict__ attr,
             float* __restrict__ gstats) {
  const int tid  = threadIdx.x;
  const int lane = tid & 63;
  const int wave = tid >> 6;
  const int e2   = lane >> 4;
  const int c16  = lane & 15;
  const int bid  = blockIdx.x;

  // per-lane attr weights for its 8 channels (ch = c16*8+j), f32
  float w1a0[8], w1a1[8], w1a2[8], w1a3[8];
#pragma unroll
  for (int j = 0; j < 8; ++j) {
    int ch = c16 * 8 + j;
    w1a0[j] = bf2f(w1t[ch * KP + 128]);
    w1a1[j] = bf2f(w1t[ch * KP + 129]);
    w1a2[j] = bf2f(w1t[ch * KP + 130]);
    w1a3[j] = bf2f(w1t[ch * KP + 131]);
  }

  float ssum[8], ssq[8];
#pragma unroll
  for (int j = 0; j < 8; ++j) { ssum[j] = 0.f; ssq[j] = 0.f; }

  shortx8 ysA, ydA, ysB, ydB;
  float4 atA, atB;
  int sF, dF;

  const int i0 = bid;
  {
    int eb0 = i0 * 16 + wave * 4 + e2;
    sF = ei[eb0]; dF = ei[E_EDGES + eb0];
    unsigned rs = (unsigned)sF;
    unsigned rd = ((unsigned)sF & ~(unsigned)(NNODES - 1)) | ((unsigned)dF & (NNODES - 1));
    int i1c = (i0 + SGRID < NIT) ? i0 + SGRID : i0;
    int eb1 = i1c * 16 + wave * 4 + e2;
    sF = ei[eb1]; dF = ei[E_EDGES + eb1];
    ysA = *(const shortx8*)(Ys + rs * HCH + c16 * 8);
    ydA = *(const shortx8*)(Yd + rd * HCH + c16 * 8);
    atA = *(const float4*)(attr + eb0 * 4);
  }

  auto body = [&](shortx8& ysC, shortx8& ydC, float4& atC,
                  shortx8& ysN, shortx8& ydN, float4& atN, int i) {
    int i1 = i + SGRID;
    if (i1 < NIT) {
      unsigned rs = (unsigned)sF;
      unsigned rd = ((unsigned)sF & ~(unsigned)(NNODES - 1)) | ((unsigned)dF & (NNODES - 1));
      int i2c = (i1 + SGRID < NIT) ? i1 + SGRID : i1;
      int eb2 = i2c * 16 + wave * 4 + e2;
      sF = ei[eb2]; dF = ei[E_EDGES + eb2];
      ysN = *(const shortx8*)(Ys + rs * HCH + c16 * 8);
      ydN = *(const shortx8*)(Yd + rd * HCH + c16 * 8);
      atN = *(const float4*)(attr + (i1 * 16 + wave * 4 + e2) * 4);
    }
    SB();
    float a0 = atC.x, a1 = atC.y, a2 = atC.z, a3 = atC.w;
#pragma unroll
    for (int j = 0; j < 8; ++j) {
      float h = bf2f((unsigned short)ysC[j]) + bf2f((unsigned short)ydC[j]);
      h = fmaf(a0, w1a0[j], h); h = fmaf(a1, w1a1[j], h);
      h = fmaf(a2, w1a2[j], h); h = fmaf(a3, w1a3[j], h);
      ssum[j] += h;
      ssq[j] = fmaf(h, h, ssq[j]);
    }
  };

  int i = i0;
  for (;;) {
    body(ysA, ydA, atA, ysB, ydB, atB, i);
    i += SGRID; if (i >= NIT) break;
    body(ysB, ydB, atB, ysA, ydA, atA, i);
    i += SGRID; if (i >= NIT) break;
  }

  // reduce over the 4 e2 copies (lanes l, l^16, l^32, l^48 share c16)
#pragma unroll
  for (int j = 0; j < 8; ++j) {
    ssum[j] += __shfl_xor(ssum[j], 16); ssum[j] += __shfl_xor(ssum[j], 32);
    ssq[j]  += __shfl_xor(ssq[j], 16);  ssq[j]  += __shfl_xor(ssq[j], 32);
  }
  if (e2 == 0) {
    float* gs = gstats + (bid & (NSPREAD - 1)) * 2 * HCH;
#pragma unroll
    for (int j = 0; j < 8; ++j) {
      atomicAdd(&gs[c16 * 8 + j], ssum[j]);
      atomicAdd(&gs[HCH + c16 * 8 + j], ssq[j]);
    }
  }
}

// --------------------------------------------------------------- final ----
__global__ void k_final(const float* __restrict__ gstats,
                        const float* __restrict__ gamma,
                        const float* __restrict__ beta,
                        const float* __restrict__ W2,
                        float* __restrict__ fconst) {
  int c = threadIdx.x;
  if (c < HCH) {
    float S = 0.f, Q = 0.f;
    for (int i = 0; i < NSPREAD; ++i) {
      S += gstats[i * 2 * HCH + c];
      Q += gstats[i * 2 * HCH + HCH + c];
    }
    float inv = 1.0f / (float)E_EDGES;
    float mu = S * inv;
    float var = Q * inv - mu * mu;
    float rstd = rsqrtf(var + 1e-5f);
    float a = gamma[c] * rstd;
    fconst[c] = a;                       // A
    fconst[HCH + c] = beta[c] - mu * a;  // B
    fconst[2 * HCH + c] = W2[c];         // W2
  }
}

// ----------------------------------------------------------------- out ----
// Same gather structure as k_stats; epilogue: p = A*h+B, LReLU, *W2,
// reduce over c16 (shfl 1,2,4,8), store out[e] + b2. No atomics.
__global__ __launch_bounds__(256, 4)
void k_out(const unsigned short* __restrict__ Ys, const unsigned short* __restrict__ Yd,
           const unsigned short* __restrict__ w1t,
           const int* __restrict__ ei, const float* __restrict__ attr,
           const float* __restrict__ fconst, const float* __restrict__ b2,
           float* __restrict__ out) {
  const int tid  = threadIdx.x;
  const int lane = tid & 63;
  const int wave = tid >> 6;
  const int e2   = lane >> 4;
  const int c16  = lane & 15;
  const int bid  = blockIdx.x;

  float w1a0[8], w1a1[8], w1a2[8], w1a3[8];
  float cA[8], cB[8], cW[8];
#pragma unroll
  for (int j = 0; j < 8; ++j) {
    int ch = c16 * 8 + j;
    w1a0[j] = bf2f(w1t[ch * KP + 128]);
    w1a1[j] = bf2f(w1t[ch * KP + 129]);
    w1a2[j] = bf2f(w1t[ch * KP + 131 - 1]);   // 130
    w1a3[j] = bf2f(w1t[ch * KP + 131]);
    cA[j] = fconst[ch];
    cB[j] = fconst[HCH + ch];
    cW[j] = fconst[2 * HCH + ch];
  }
  const float b2v = b2[0];

  shortx8 ysA, ydA, ysB, ydB;
  float4 atA, atB;
  int sF, dF;

  const int i0 = bid;
  {
    int eb0 = i0 * 16 + wave * 4 + e2;
    sF = ei[eb0]; dF = ei[E_EDGES + eb0];
    unsigned rs = (unsigned)sF;
    unsigned rd = ((unsigned)sF & ~(unsigned)(NNODES - 1)) | ((unsigned)dF & (NNODES - 1));
    int i1c = (i0 + SGRID < NIT) ? i0 + SGRID : i0;
    int eb1 = i1c * 16 + wave * 4 + e2;
    sF = ei[eb1]; dF = ei[E_EDGES + eb1];
    ysA = *(const shortx8*)(Ys + rs * HCH + c16 * 8);
    ydA = *(const shortx8*)(Yd + rd * HCH + c16 * 8);
    atA = *(const float4*)(attr + eb0 * 4);
  }

  auto body = [&](shortx8& ysC, shortx8& ydC, float4& atC,
                  shortx8& ysN, shortx8& ydN, float4& atN, int i) {
    int i1 = i + SGRID;
    if (i1 < NIT) {
      unsigned rs = (unsigned)sF;
      unsigned rd = ((unsigned)sF & ~(unsigned)(NNODES - 1)) | ((unsigned)dF & (NNODES - 1));
      int i2c = (i1 + SGRID < NIT) ? i1 + SGRID : i1;
      int eb2 = i2c * 16 + wave * 4 + e2;
      sF = ei[eb2]; dF = ei[E_EDGES + eb2];
      ysN = *(const shortx8*)(Ys + rs * HCH + c16 * 8);
      ydN = *(const shortx8*)(Yd + rd * HCH + c16 * 8);
      atN = *(const float4*)(attr + (i1 * 16 + wave * 4 + e2) * 4);
    }
    SB();
    float a0 = atC.x, a1 = atC.y, a2 = atC.z, a3 = atC.w;
    float part = 0.f;
#pragma unroll
    for (int j = 0; j < 8; ++j) {
      float h = bf2f((unsigned short)ysC[j]) + bf2f((unsigned short)ydC[j]);
      h = fmaf(a0, w1a0[j], h); h = fmaf(a1, w1a1[j], h);
      h = fmaf(a2, w1a2[j], h); h = fmaf(a3, w1a3[j], h);
      float p = fmaf(cA[j], h, cB[j]);
      float lr = fmaxf(p, 0.2f * p);          // LeakyReLU for either sign
      part = fmaf(cW[j], lr, part);
    }
    // sum over the 16 channel-slices (c16 = low 4 lane bits)
    part += __shfl_xor(part, 1);
    part += __shfl_xor(part, 2);
    part += __shfl_xor(part, 4);
    part += __shfl_xor(part, 8);
    if (c16 == 0) out[i * 16 + wave * 4 + e2] = part + b2v;
  };

  int i = i0;
  for (;;) {
    body(ysA, ydA, atA, ysB, ydB, atB, i);
    i += SGRID; if (i >= NIT) break;
    body(ysB, ydB, atB, ysA, ydA, atA, i);
    i += SGRID; if (i >= NIT) break;
  }
}

// -------------------------------------------------------------- launch ----
extern "C" void kernel_launch(void* const* d_in, const int* in_sizes, int n_in,
                              void* d_out, int out_size, void* d_ws, size_t ws_size,
                              hipStream_t stream) {
  const float* z     = (const float*)d_in[0];
  const float* attr  = (const float*)d_in[1];
  const float* W1    = (const float*)d_in[2];
  const float* b1    = (const float*)d_in[3];
  const float* gamma = (const float*)d_in[4];
  const float* beta  = (const float*)d_in[5];
  const float* W2    = (const float*)d_in[6];
  const float* b2    = (const float*)d_in[7];
  const int*   ei    = (const int*)d_in[8];
  float* out = (float*)d_out;

  char* ws = (char*)d_ws;
  unsigned short* zb  = (unsigned short*)ws;                  //  8,388,608 B
  unsigned short* w1t = (unsigned short*)(ws + 8388608);      //     34,816 B
  float* gstats       = (float*)(ws + 8423424);               //      8,192 B
  float* fconst       = (float*)(ws + 8431616);               //      1,536 B
  unsigned short* Ysb = (unsigned short*)(ws + 8433152);      // 16,777,216 B
  unsigned short* Ydb = (unsigned short*)(ws + 25210368);     // 16,777,216 B
  // total ws: 41,987,584 B

  k_prep<<<ZBLK + WBLK + 1, 256, 0, stream>>>(z, W1, zb, w1t, gstats);
  k_ygemm<<<2048, 256, 0, stream>>>(zb, w1t, b1, Ysb, Ydb);
  k_stats<<<SGRID, 256, 0, stream>>>(Ysb, Ydb, w1t, ei, attr, gstats);
  k_final<<<1, 128, 0, stream>>>(gstats, gamma, beta, W2, fconst);
  k_out<<<SGRID, 256, 0, stream>>>(Ysb, Ydb, w1t, ei, attr, fconst, b2, out);
}